// Round 13
// baseline (40.687 us; speedup 1.0000x reference)
//
#include <hip/hip_runtime.h>
#include <hip/hip_fp16.h>

typedef unsigned int uint;
typedef __attribute__((ext_vector_type(2))) _Float16 half2_t;
typedef __attribute__((ext_vector_type(2))) __fp16 fp16x2_t;

#define NUM 2048
#define SP 12
#define WIN 33
#define RSTR 20                         // row stride, dwords (40 f16)
#define HS_STRIDE 14
#define HSE_DW 1980                     // 99*20 : end of E window
#define HSO_DW (HSE_DW + 462)           // 2442
#define TOT_DW (HSO_DW + 462)           // 2904 dw = 11616 B -> 13 blocks/CU
// VS overlays the dead E-copy region after cross:
#define VSE_DW 0
#define VSO_DW 400
#define VSTR 16

union U32H2 { uint u; half2_t h; };
__device__ __forceinline__ half2_t uh2(uint u){ U32H2 p; p.u=u; return p.h; }

#if __has_builtin(__builtin_amdgcn_fdot2)
__device__ __forceinline__ float fdot2(uint a, uint b, float c) {
    return __builtin_amdgcn_fdot2(uh2(a), uh2(b), c, false);
}
#else
__device__ __forceinline__ float fdot2(uint a, uint b, float c) {
    half2_t A = uh2(a), B = uh2(b);
    return fmaf((float)A.y, (float)B.y, fmaf((float)A.x, (float)B.x, c));
}
#endif

#if __has_builtin(__builtin_amdgcn_alignbit)
__device__ __forceinline__ uint alnb(uint hi, uint lo, uint sh) {
    return __builtin_amdgcn_alignbit(hi, lo, sh);
}
#else
__device__ __forceinline__ uint alnb(uint hi, uint lo, uint sh) {
    return (uint)(((((unsigned long long)hi) << 32) | lo) >> sh);
}
#endif

__device__ __forceinline__ uint packh2(float a, float b) {
    return (uint)__half_as_ushort(__float2half(a)) |
           ((uint)__half_as_ushort(__float2half(b)) << 16);
}

#if __has_builtin(__builtin_amdgcn_cvt_pkrtz)
__device__ __forceinline__ uint pkh2(float a, float b) {
    union { uint u; fp16x2_t h; } p;
    p.h = __builtin_amdgcn_cvt_pkrtz(a, b);
    return p.u;
}
#else
__device__ __forceinline__ uint pkh2(float a, float b) { return packh2(a, b); }
#endif

__global__ __launch_bounds__(64, 4) void simmap_kernel(
    const float* __restrict__ img, const float* __restrict__ img_sr,
    const float* __restrict__ sigma, const int* __restrict__ coords,
    float* __restrict__ out)
{
    __shared__ __align__(16) uint lds[TOT_DW];
    float* lf = (float*)lds;

    const int n = blockIdx.x;
    const int imgid = blockIdx.y;
    const float* im = imgid ? img_sr : img;
    const int l = threadIdx.x;       // single wave per block
    const int r0 = coords[2*n];
    const int c0 = coords[2*n+1];

    // ---- stage: one lane per (c,r) row; E copy only, b128 writes ----
    const bool interior = (r0 >= 16 && r0 < 240 && c0 >= 16 && c0 < 240);
    #pragma unroll 1
    for (int task = l; task < 99; task += 64) {
        const int c = task / 33;
        const int r = task - c*33;
        const int ri = r0 + r - 16;
        const float* rowp = im + c*65536 + ri*256 + (c0 - 16);
        uint Edw[17];
        if (interior) {
            #pragma unroll
            for (int k = 0; k < 16; ++k)
                Edw[k] = pkh2(rowp[2*k], rowp[2*k+1]);
            Edw[16] = pkh2(rowp[32], 0.f);
        } else {
            const bool rv = ((uint)ri < 256u);
            #pragma unroll
            for (int k = 0; k < 16; ++k) {
                float f0 = (rv && (uint)(c0 - 16 + 2*k)     < 256u) ? rowp[2*k]   : 0.f;
                float f1 = (rv && (uint)(c0 - 16 + 2*k + 1) < 256u) ? rowp[2*k+1] : 0.f;
                Edw[k] = pkh2(f0, f1);
            }
            float f0 = (rv && (uint)(c0 + 16) < 256u) ? rowp[32] : 0.f;
            Edw[16] = pkh2(f0, 0.f);
        }
        uint* pE = lds + (uint)task * RSTR;
        ((uint4*)pE)[0] = uint4{Edw[0],Edw[1],Edw[2],Edw[3]};
        ((uint4*)pE)[1] = uint4{Edw[4],Edw[5],Edw[6],Edw[7]};
        ((uint4*)pE)[2] = uint4{Edw[8],Edw[9],Edw[10],Edw[11]};
        ((uint4*)pE)[3] = uint4{Edw[12],Edw[13],Edw[14],Edw[15]};
        *(uint2*)(pE + 16) = uint2{Edw[16], 0u};   // E[17]=0 pad
    }
    __syncthreads();   // 1-wave block: compiles to a waitcnt fence

    // ---- hs (lanes<33): parity-packed sliding sums of squares ----
    if (l < WIN) {
        float sq[33];
        #pragma unroll
        for (int x = 0; x < 33; ++x) sq[x] = 0.f;
        #pragma unroll 1
        for (int c = 0; c < 3; ++c) {
            const uint* rp = lds + (uint)(c*WIN + l)*RSTR;
            uint U[17];
            { uint4 v = *(const uint4*)(rp);    U[0]=v.x;U[1]=v.y;U[2]=v.z;U[3]=v.w; }
            { uint4 v = *(const uint4*)(rp+4);  U[4]=v.x;U[5]=v.y;U[6]=v.z;U[7]=v.w; }
            { uint4 v = *(const uint4*)(rp+8);  U[8]=v.x;U[9]=v.y;U[10]=v.z;U[11]=v.w; }
            { uint4 v = *(const uint4*)(rp+12); U[12]=v.x;U[13]=v.y;U[14]=v.z;U[15]=v.w; }
            U[16] = rp[16];
            #pragma unroll
            for (int k = 0; k < 17; ++k) {
                half2_t h = uh2(U[k]);
                float x0 = (float)h.x, x1 = (float)h.y;
                sq[2*k] += x0*x0;
                if (2*k + 1 < 33) sq[2*k+1] += x1*x1;
            }
        }
        float s = 0.f;
        #pragma unroll
        for (int j = 0; j < 9; ++j) s += sq[j];
        lf[HSE_DW + l*HS_STRIDE + 0] = s;
        #pragma unroll
        for (int d = 1; d < 25; ++d) {
            s += sq[d+8] - sq[d-1];
            if (d & 1) lf[HSO_DW + l*HS_STRIDE + (d>>1)] = s;
            else       lf[HSE_DW + l*HS_STRIDE + (d>>1)] = s;
        }
    }

    // ---- cross term: lane owns (d0=l>>1, parity=l&1); ALL 27 rows ----
    const int parity = l & 1;
    const int d0e = (l < 50) ? (l >> 1) : 0;
    const uint psh = (uint)(parity << 4);   // 0: S=E pairs; 16: S=odd pairs

    float acc[13];
    #pragma unroll
    for (int oo = 0; oo < 13; ++oo) acc[oo] = 0.f;

    #pragma unroll 1
    for (int c = 0; c < 3; ++c) {
        #pragma unroll 1
        for (int i = 0; i < 9; ++i) {
            const uint* sp = lds + (uint)(c*WIN + d0e + i)*RSTR;
            uint E[18];
            { uint4 v = *(const uint4*)(sp);    E[0]=v.x;E[1]=v.y;E[2]=v.z;E[3]=v.w; }
            { uint4 v = *(const uint4*)(sp+4);  E[4]=v.x;E[5]=v.y;E[6]=v.z;E[7]=v.w; }
            { uint4 v = *(const uint4*)(sp+8);  E[8]=v.x;E[9]=v.y;E[10]=v.z;E[11]=v.w; }
            { uint4 v = *(const uint4*)(sp+12); E[12]=v.x;E[13]=v.y;E[14]=v.z;E[15]=v.w; }
            { uint2 v = *(const uint2*)(sp+16); E[16]=v.x; E[17]=v.y; }
            uint S[17];
            #pragma unroll
            for (int k = 0; k < 17; ++k) S[k] = alnb(E[k+1], E[k], psh);
            const uint* cp = lds + (uint)(c*WIN + SP + i)*RSTR;   // center (broadcast)
            uint cw[5];
            { uint2 v = *(const uint2*)(cp+6); cw[0]=v.x; cw[1]=v.y; }
            { uint2 v = *(const uint2*)(cp+8); cw[2]=v.x; cw[3]=v.y; }
            cw[4] = cp[10] & 0xFFFFu;                              // (c8, 0)
            #pragma unroll
            for (int oo = 0; oo < 13; ++oo) {
                float a = acc[oo];
                #pragma unroll
                for (int jj = 0; jj < 5; ++jj)
                    a = fdot2(S[oo + jj], cw[jj], a);
                acc[oo] = a;
            }
        }
    }
    __syncthreads();   // cross reads of E region done -> VS may overlay it

    // ---- VS: vertical 9-row sliding sums of hs (lanes<25) ----
    if (l < 25) {
        const int par = l & 1, col = l >> 1;
        const int hbase = (par ? HSO_DW : HSE_DW) + col;
        float f[33];
        #pragma unroll
        for (int r = 0; r < 33; ++r) f[r] = lf[hbase + r*HS_STRIDE];
        float s = 0.f;
        #pragma unroll
        for (int i = 0; i < 9; ++i) s += f[i];
        const int vbase = (par ? VSO_DW : VSE_DW) + col;
        lf[vbase] = s;
        #pragma unroll
        for (int d0 = 1; d0 < 25; ++d0) {
            s += f[d0+8] - f[d0-1];
            lf[vbase + d0*VSTR] = s;
        }
    }
    __syncthreads();

    // ---- epilogue (lanes<50): acc is f32 in registers ----
    if (l >= 50) return;
    const int d0 = l >> 1;

    const float* vr = lf + (parity ? VSO_DW : VSE_DW) + d0*VSTR;
    float4 v0 = *(const float4*)(vr);
    float4 v1 = *(const float4*)(vr + 4);
    float4 v2 = *(const float4*)(vr + 8);
    float bs[13] = {v0.x,v0.y,v0.z,v0.w,v1.x,v1.y,v1.z,v1.w,
                    v2.x,v2.y,v2.z,v2.w,vr[12]};

    float cc = 0.f;
    #pragma unroll
    for (int i = 0; i < 9; ++i) cc += lf[HSE_DW + (SP + i)*HS_STRIDE + 6];

    const float sg = fmaxf(sigma[0], 0.f);
    const float scl = -1.f / (243.f * sg);
    float* op = out + (size_t)(imgid*NUM + n)*625 + d0*25 + parity;
    #pragma unroll
    for (int oo = 0; oo < 13; ++oo) {
        if (parity && oo == 12) break;      // odd half has 12 outputs
        op[2*oo] = __expf((bs[oo] + cc - 2.f*acc[oo]) * scl + 1e-20f);
    }
}

extern "C" void kernel_launch(void* const* d_in, const int* in_sizes, int n_in,
                              void* d_out, int out_size, void* d_ws, size_t ws_size,
                              hipStream_t stream) {
    const float* img    = (const float*)d_in[0];
    const float* img_sr = (const float*)d_in[1];
    const float* sigma  = (const float*)d_in[2];
    const int*   coords = (const int*)d_in[3];
    float* out = (float*)d_out;
    dim3 grid(NUM, 2);
    simmap_kernel<<<grid, dim3(64), 0, stream>>>(img, img_sr, sigma, coords, out);
}

// Round 14
// 35.031 us; speedup vs baseline: 1.1615x; 1.1615x over previous
//
#include <hip/hip_runtime.h>
#include <hip/hip_fp16.h>

typedef unsigned int uint;
typedef __attribute__((ext_vector_type(2))) _Float16 half2_t;
typedef __attribute__((ext_vector_type(2))) __fp16 fp16x2_t;

#define NUM 2048
#define SP 12
#define WIN 33
#define RSTR 20                         // window row stride, dwords (40 f16)
#define OD_DW (3*WIN*RSTR)              // 1980: O copy dword base
#define HS_STRIDE 16                    // hs row stride (16B-aligned rows)
#define HSE_DW (2*OD_DW)                // 3960
#define HSO_DW (HSE_DW + WIN*HS_STRIDE) // 4488
#define TOT_DW (HSO_DW + WIN*HS_STRIDE) // 5016 dw = 20064 B -> 8 blocks/CU
// post-cross overlays (E/O window regions are dead after the cross phase):
#define PARTS_DW 0                      // 4*50*8 = 1600 dw <= 1980 (E region)
#define PSTR 8
#define VSE_DW OD_DW                    // 1980..2380 (O region)
#define VSO_DW (OD_DW + 400)            // 2380..2780
#define VSTR 16                         // VS row stride (16B-aligned rows)

union U32H2 { uint u; half2_t h; };
__device__ __forceinline__ half2_t uh2(uint u){ U32H2 p; p.u=u; return p.h; }

#if __has_builtin(__builtin_amdgcn_fdot2)
__device__ __forceinline__ float fdot2(uint a, uint b, float c) {
    return __builtin_amdgcn_fdot2(uh2(a), uh2(b), c, false);
}
#else
__device__ __forceinline__ float fdot2(uint a, uint b, float c) {
    half2_t A = uh2(a), B = uh2(b);
    return fmaf((float)A.y, (float)B.y, fmaf((float)A.x, (float)B.x, c));
}
#endif

__device__ __forceinline__ uint packh2(float a, float b) {
    return (uint)__half_as_ushort(__float2half(a)) |
           ((uint)__half_as_ushort(__float2half(b)) << 16);
}

#if __has_builtin(__builtin_amdgcn_cvt_pkrtz)
__device__ __forceinline__ uint pkh2(float a, float b) {
    union { uint u; fp16x2_t h; } p;
    p.h = __builtin_amdgcn_cvt_pkrtz(a, b);
    return p.u;
}
#else
__device__ __forceinline__ uint pkh2(float a, float b) { return packh2(a, b); }
#endif

__global__ __launch_bounds__(256, 6) void simmap_kernel(
    const float* __restrict__ img, const float* __restrict__ img_sr,
    const float* __restrict__ sigma, const int* __restrict__ coords,
    float* __restrict__ out)
{
    __shared__ __align__(16) uint lds[TOT_DW];
    __half* wh = (__half*)lds;
    float*  lf = (float*)lds;

    const int n = blockIdx.x;
    const int imgid = blockIdx.y;
    const float* im = imgid ? img_sr : img;
    const int t = threadIdx.x;
    const int w = t >> 6;
    const int l = t & 63;
    const int r0 = coords[2*n];
    const int c0 = coords[2*n+1];

    // ---- stage: one thread per (c,r) row; pack E/O dwords in regs, b128 writes ----
    if (t < 99) {
        const int c = t / 33;
        const int r = t - c*33;
        const int ri = r0 + r - 16;
        const float* rowp = im + c*65536 + ri*256 + (c0 - 16);
        uint Edw[17], Odw[17];
        if (r0 >= 16 && r0 < 240 && c0 >= 16 && c0 < 240) {
            float f0 = rowp[0];
            #pragma unroll
            for (int k = 0; k < 16; ++k) {
                float f1 = rowp[2*k+1];
                float f2 = rowp[2*k+2];
                Edw[k] = pkh2(f0, f1);
                Odw[k] = pkh2(f1, f2);
                f0 = f2;
            }
            Edw[16] = pkh2(f0, 0.f);
            Odw[16] = 0u;
        } else {
            const bool rv = ((uint)ri < 256u);
            float f0 = (rv && (uint)(c0 - 16) < 256u) ? rowp[0] : 0.f;
            #pragma unroll
            for (int k = 0; k < 16; ++k) {
                const int x1 = 2*k + 1, x2 = 2*k + 2;
                float f1 = (rv && (uint)(c0 - 16 + x1) < 256u) ? rowp[x1] : 0.f;
                float f2 = (rv && (uint)(c0 - 16 + x2) < 256u) ? rowp[x2] : 0.f;
                Edw[k] = pkh2(f0, f1);
                Odw[k] = pkh2(f1, f2);
                f0 = f2;
            }
            Edw[16] = pkh2(f0, 0.f);
            Odw[16] = 0u;
        }
        uint* pE = lds + (uint)t * RSTR;
        uint* pO = lds + OD_DW + (uint)t * RSTR;
        ((uint4*)pE)[0] = uint4{Edw[0],Edw[1],Edw[2],Edw[3]};
        ((uint4*)pE)[1] = uint4{Edw[4],Edw[5],Edw[6],Edw[7]};
        ((uint4*)pE)[2] = uint4{Edw[8],Edw[9],Edw[10],Edw[11]};
        ((uint4*)pE)[3] = uint4{Edw[12],Edw[13],Edw[14],Edw[15]};
        pE[16] = Edw[16];
        ((uint4*)pO)[0] = uint4{Odw[0],Odw[1],Odw[2],Odw[3]};
        ((uint4*)pO)[1] = uint4{Odw[4],Odw[5],Odw[6],Odw[7]};
        ((uint4*)pO)[2] = uint4{Odw[8],Odw[9],Odw[10],Odw[11]};
        ((uint4*)pO)[3] = uint4{Odw[12],Odw[13],Odw[14],Odw[15]};
        pO[16] = Odw[16];
    }
    __syncthreads();

    // ---- hs (wave0, lanes<33): sliding sums of squares; vector chunk writes ----
    if (w == 0 && l < WIN) {
        float sq[33];
        #pragma unroll
        for (int x = 0; x < 33; ++x) sq[x] = 0.f;
        #pragma unroll 1
        for (int c = 0; c < 3; ++c) {
            const uint* rp = lds + (uint)(c*WIN + l)*RSTR;
            uint U[17];
            { uint4 v = *(const uint4*)(rp);    U[0]=v.x;U[1]=v.y;U[2]=v.z;U[3]=v.w; }
            { uint4 v = *(const uint4*)(rp+4);  U[4]=v.x;U[5]=v.y;U[6]=v.z;U[7]=v.w; }
            { uint4 v = *(const uint4*)(rp+8);  U[8]=v.x;U[9]=v.y;U[10]=v.z;U[11]=v.w; }
            { uint4 v = *(const uint4*)(rp+12); U[12]=v.x;U[13]=v.y;U[14]=v.z;U[15]=v.w; }
            U[16] = rp[16];
            #pragma unroll
            for (int k = 0; k < 17; ++k) {
                half2_t h = uh2(U[k]);
                float x0 = (float)h.x, x1 = (float)h.y;
                sq[2*k] += x0*x0;
                if (2*k + 1 < 33) sq[2*k+1] += x1*x1;
            }
        }
        float hse[13], hso[12];
        float s = 0.f;
        #pragma unroll
        for (int j = 0; j < 9; ++j) s += sq[j];
        hse[0] = s;
        #pragma unroll
        for (int d = 1; d < 25; ++d) {
            s += sq[d+8] - sq[d-1];
            if (d & 1) hso[d>>1] = s;
            else       hse[d>>1] = s;
        }
        // swizzled b128 writes: chunk q stored at offset 4*(q ^ ((l>>1)&3))
        const uint sxh = ((uint)l >> 1) & 3u;
        float* he = lf + HSE_DW + l*HS_STRIDE;
        *(float4*)(he + 4*(0u^sxh)) = float4{hse[0], hse[1], hse[2], hse[3]};
        *(float4*)(he + 4*(1u^sxh)) = float4{hse[4], hse[5], hse[6], hse[7]};
        *(float4*)(he + 4*(2u^sxh)) = float4{hse[8], hse[9], hse[10], hse[11]};
        *(float4*)(he + 4*(3u^sxh)) = float4{hse[12], 0.f, 0.f, 0.f};
        float* ho = lf + HSO_DW + l*HS_STRIDE;
        *(float4*)(ho + 4*(0u^sxh)) = float4{hso[0], hso[1], hso[2], hso[3]};
        *(float4*)(ho + 4*(1u^sxh)) = float4{hso[4], hso[5], hso[6], hso[7]};
        *(float4*)(ho + 4*(2u^sxh)) = float4{hso[8], hso[9], hso[10], hso[11]};
    }

    // ---- cross term: lane owns (d0=l>>1, parity=l&1); o = 2*oo+parity ----
    const int lpar = l & 1;
    const int d0e = (l < 50) ? (l >> 1) : 0;
    const uint sbase = lpar ? (uint)OD_DW : 0u;

    float acc[13];
    #pragma unroll
    for (int oo = 0; oo < 13; ++oo) acc[oo] = 0.f;

    // rows 0..26 split 4/7/8/8 across waves: 0-3 / 4-10 / 11-18 / 19-26
    const int base  = (w == 0) ? 0 : (w == 1) ? 4 : (w == 2) ? 11 : 19;
    const int nrows = (w == 0) ? 4 : (w == 1) ? 7 : 8;

    #pragma unroll 1
    for (int ridx = base; ridx < base + nrows; ++ridx) {
        const int c = ridx / 9;
        const int i = ridx - 9*c;
        const uint* sp = lds + sbase + (uint)(c*WIN + d0e + i)*RSTR;
        uint S[17];
        { uint4 v = *(const uint4*)(sp);    S[0]=v.x;S[1]=v.y;S[2]=v.z;S[3]=v.w; }
        { uint4 v = *(const uint4*)(sp+4);  S[4]=v.x;S[5]=v.y;S[6]=v.z;S[7]=v.w; }
        { uint4 v = *(const uint4*)(sp+8);  S[8]=v.x;S[9]=v.y;S[10]=v.z;S[11]=v.w; }
        { uint4 v = *(const uint4*)(sp+12); S[12]=v.x;S[13]=v.y;S[14]=v.z;S[15]=v.w; }
        S[16] = sp[16];
        const uint* cp = lds + (uint)(c*WIN + SP + i)*RSTR;   // center row (broadcast)
        uint cw[5];
        { uint2 v = *(const uint2*)(cp+6); cw[0]=v.x; cw[1]=v.y; }
        { uint2 v = *(const uint2*)(cp+8); cw[2]=v.x; cw[3]=v.y; }
        cw[4] = cp[10] & 0xFFFFu;                              // (c8, 0)
        #pragma unroll
        for (int oo = 0; oo < 13; ++oo) {
            float a = acc[oo];
            #pragma unroll
            for (int jj = 0; jj < 5; ++jj)
                a = fdot2(S[oo + jj], cw[jj], a);
            acc[oo] = a;
        }
    }

    __syncthreads();   // cross done -> E/O window regions are dead, overlay them

    // ---- publish partials (f16-packed, 2x b128) into former E region ----
    if (l < 50) {
        uint* dst = lds + PARTS_DW + (uint)(w*50 + l)*PSTR;
        uint4 p0, p1;
        p0.x = packh2(acc[0],  acc[1]);  p0.y = packh2(acc[2],  acc[3]);
        p0.z = packh2(acc[4],  acc[5]);  p0.w = packh2(acc[6],  acc[7]);
        p1.x = packh2(acc[8],  acc[9]);  p1.y = packh2(acc[10], acc[11]);
        p1.z = packh2(acc[12], 0.f);     p1.w = 0u;
        ((uint4*)dst)[0] = p0;
        ((uint4*)dst)[1] = p1;
    }
    // ---- VS: vertical 9-row sums of hs, into former O region (wave1, lanes<25) ----
    if (w == 1 && l < 25) {
        const int par = l & 1, col = l >> 1;
        const int qc = col >> 2, kc = col & 3;
        const int hbase = par ? HSO_DW : HSE_DW;
        float f[33];
        #pragma unroll
        for (int r = 0; r < 33; ++r)
            f[r] = lf[hbase + r*HS_STRIDE + 4*((uint)qc ^ (((uint)r >> 1) & 3u)) + kc];
        float s = 0.f;
        #pragma unroll
        for (int i = 0; i < 9; ++i) s += f[i];
        const int vbase = (par ? VSO_DW : VSE_DW) + col;
        lf[vbase] = s;
        #pragma unroll
        for (int d0 = 1; d0 < 25; ++d0) {
            s += f[d0+8] - f[d0-1];
            lf[vbase + d0*VSTR] = s;
        }
    }
    __syncthreads();

    // ---- distributed epilogue: wave w owns tasks 13w .. 13w+12 ----
    const int T = 13*w + l;
    if (l >= 13 || T >= 50) return;
    const int d0 = T >> 1;
    const int parity = T & 1;

    float cr[13];
    #pragma unroll
    for (int oo = 0; oo < 13; ++oo) cr[oo] = 0.f;
    #pragma unroll
    for (int ww = 0; ww < 4; ++ww) {
        const uint* src = lds + PARTS_DW + (uint)(ww*50 + T)*PSTR;
        uint4 a = ((const uint4*)src)[0];
        uint4 b = ((const uint4*)src)[1];
        half2_t h;
        h = uh2(a.x); cr[0] += (float)h.x; cr[1] += (float)h.y;
        h = uh2(a.y); cr[2] += (float)h.x; cr[3] += (float)h.y;
        h = uh2(a.z); cr[4] += (float)h.x; cr[5] += (float)h.y;
        h = uh2(a.w); cr[6] += (float)h.x; cr[7] += (float)h.y;
        h = uh2(b.x); cr[8] += (float)h.x; cr[9] += (float)h.y;
        h = uh2(b.y); cr[10] += (float)h.x; cr[11] += (float)h.y;
        h = uh2(b.z); cr[12] += (float)h.x;
    }

    const float* vr = lf + (parity ? VSO_DW : VSE_DW) + d0*VSTR;
    float4 v0 = *(const float4*)(vr);
    float4 v1 = *(const float4*)(vr + 4);
    float4 v2 = *(const float4*)(vr + 8);
    float bs[13] = {v0.x,v0.y,v0.z,v0.w,v1.x,v1.y,v1.z,v1.w,
                    v2.x,v2.y,v2.z,v2.w,vr[12]};

    // cc = vertical sum of hs_E at center column = VS_E[d0=12][col=6]
    const float cc = lf[VSE_DW + 12*VSTR + 6];

    const float sg = fmaxf(sigma[0], 0.f);
    const float scl = -1.f / (243.f * sg);
    float* op = out + (size_t)(imgid*NUM + n)*625 + d0*25 + parity;
    #pragma unroll
    for (int oo = 0; oo < 13; ++oo) {
        if (parity && oo == 12) break;      // odd half has 12 outputs
        op[2*oo] = __expf((bs[oo] + cc - 2.f*cr[oo]) * scl + 1e-20f);
    }
}

extern "C" void kernel_launch(void* const* d_in, const int* in_sizes, int n_in,
                              void* d_out, int out_size, void* d_ws, size_t ws_size,
                              hipStream_t stream) {
    const float* img    = (const float*)d_in[0];
    const float* img_sr = (const float*)d_in[1];
    const float* sigma  = (const float*)d_in[2];
    const int*   coords = (const int*)d_in[3];
    float* out = (float*)d_out;
    dim3 grid(NUM, 2);
    simmap_kernel<<<grid, dim3(256), 0, stream>>>(img, img_sr, sigma, coords, out);
}